// Round 4
// baseline (389.348 us; speedup 1.0000x reference)
//
#include <hip/hip_runtime.h>

// out[b] = clip( hardswish( dot(x[b,:], colsum(y)) ) + noise[b], -0.5, 0.5 )
// B = 8192, F = 4096, fp32. Memory-bound: compulsory 256 MB (x + y) -> ~41 us floor.
//
// R1: 64-block colsum latency-bound (101 us). R2: 3-dispatch chain, 105 us total,
// tiny colsum_final + block-per-row rowdot suspected stragglers. R3: cooperative
// launch silently failed (absmax 0.5 = never ran). R4 design: two ordinary
// dispatches; final reduce fused into colsum via last-block ticket (per strip);
// rowdot as wave-per-row (no LDS, no syncthreads).

namespace {

constexpr int F      = 4096;
constexpr int B      = 8192;
constexpr int NTHR   = 256;
constexpr int NSTRIP = 4;               // 256 thr * float4 = 1024 cols per strip
constexpr int NSLAB  = 512;             // row slabs -> 4*512 = 2048 blocks
constexpr int RPS    = B / NSLAB;       // 16 rows per slab

__device__ __forceinline__ void f4_add(float4& a, const float4 b) {
    a.x += b.x; a.y += b.y; a.z += b.z; a.w += b.w;
}
__device__ __forceinline__ void f4_fma(float& a, const float4 xv, const float4 yv) {
    a = fmaf(xv.x, yv.x, a); a = fmaf(xv.y, yv.y, a);
    a = fmaf(xv.z, yv.z, a); a = fmaf(xv.w, yv.w, a);
}

// Kernel A: block (strip s, slab p) column-sums 16 rows of y into
// partial[p][s*1024 ...]; the last block of each strip (ticket) then reduces
// the strip's 512 partials into ysum. Counters must be zeroed pre-launch.
__global__ __launch_bounds__(NTHR) void colsum_k(
    const float* __restrict__ y, float* __restrict__ partial,
    float* __restrict__ ysum, unsigned int* __restrict__ counters)
{
    const int s  = blockIdx.x;              // strip 0..3
    const int p  = blockIdx.y;              // slab  0..511
    const int t  = threadIdx.x;
    const int c4 = s * NTHR + t;            // float4 column index

    const long row0 = (long)p * RPS;
    float4 acc = {0.f, 0.f, 0.f, 0.f};
#pragma unroll
    for (int r = 0; r < RPS; ++r)
        f4_add(acc, reinterpret_cast<const float4*>(y + (row0 + r) * F)[c4]);
    reinterpret_cast<float4*>(partial + (size_t)p * F)[c4] = acc;

    // Release our partial, then take a ticket (device-scope atomic, m20).
    __threadfence();
    __shared__ unsigned int ticket;
    if (t == 0) ticket = atomicAdd(&counters[s], 1u);
    __syncthreads();

    if (ticket == NSLAB - 1) {              // all 512 slabs of strip s done
        __threadfence();                    // acquire side
        float4 a = {0.f, 0.f, 0.f, 0.f};
#pragma unroll 8
        for (int q = 0; q < NSLAB; ++q)
            f4_add(a, reinterpret_cast<const float4*>(partial + (size_t)q * F)[c4]);
        reinterpret_cast<float4*>(ysum)[c4] = a;
    }
}

// Kernel B: wave-per-row dot(x[b,:], ysum) -> hardswish -> +noise -> hardtanh.
// 2048 blocks x 4 waves = 8192 rows. No LDS, no __syncthreads.
__global__ __launch_bounds__(NTHR) void rowdot_k(
    const float* __restrict__ x, const float* __restrict__ ysum,
    const float* __restrict__ noise, float* __restrict__ out)
{
    const int wid  = threadIdx.x >> 6;
    const int lane = threadIdx.x & 63;
    const int b    = blockIdx.x * 4 + wid;

    const float4* xr = reinterpret_cast<const float4*>(x + (size_t)b * F);
    const float4* ys = reinterpret_cast<const float4*>(ysum);

    float a0 = 0.f, a1 = 0.f, a2 = 0.f, a3 = 0.f;
#pragma unroll
    for (int g = 0; g < 16; g += 4) {
        f4_fma(a0, xr[(g + 0) * 64 + lane], ys[(g + 0) * 64 + lane]);
        f4_fma(a1, xr[(g + 1) * 64 + lane], ys[(g + 1) * 64 + lane]);
        f4_fma(a2, xr[(g + 2) * 64 + lane], ys[(g + 2) * 64 + lane]);
        f4_fma(a3, xr[(g + 3) * 64 + lane], ys[(g + 3) * 64 + lane]);
    }
    float p = (a0 + a1) + (a2 + a3);
#pragma unroll
    for (int off = 32; off > 0; off >>= 1) p += __shfl_xor(p, off);

    if (lane == 0) {
        const float s = p;
        const float h = s * fminf(fmaxf(s + 3.0f, 0.0f), 6.0f) * (1.0f / 6.0f);
        const float r = h + noise[b];       // logsumexp over singleton == identity
        out[b] = fminf(fmaxf(r, -0.5f), 0.5f);
    }
}

} // namespace

extern "C" void kernel_launch(void* const* d_in, const int* in_sizes, int n_in,
                              void* d_out, int out_size, void* d_ws, size_t ws_size,
                              hipStream_t stream)
{
    const float* x     = (const float*)d_in[0];   // (B, F)
    const float* y     = (const float*)d_in[1];   // (B, F)
    const float* noise = (const float*)d_in[2];   // (B, 1)
    float*       out   = (float*)d_out;           // (B, 1) fp32

    // ws layout: partial[NSLAB][F] (8 MB) | ysum[F] (16 KB) | counters[4]
    float*        partial  = (float*)d_ws;
    float*        ysum     = partial + (size_t)NSLAB * F;
    unsigned int* counters = (unsigned int*)(ysum + F);

    hipMemsetAsync(counters, 0, NSTRIP * sizeof(unsigned int), stream);
    colsum_k<<<dim3(NSTRIP, NSLAB), NTHR, 0, stream>>>(y, partial, ysum, counters);
    rowdot_k<<<B / 4,               NTHR, 0, stream>>>(x, ysum, noise, out);
}

// Round 5
// 50.736 us; speedup vs baseline: 7.6739x; 7.6739x over previous
//
#include <hip/hip_runtime.h>

// out[b] = clip( hardswish( dot(x[b,:], colsum(y)) ) + noise[b], -0.5, 0.5 )
// B = 8192, F = 4096, fp32. Memory-bound: compulsory 256 MB (x + y) -> ~41 us floor.
//
// Journal:
//  R1: 64-block colsum latency-bound (101 us @ 2.7% occupancy).
//  R2: 1024-block colsum + 16-block final + block-per-row rowdot = 105 us;
//      straggler = 16-block final (256 un-unrolled strided loads/thread).
//  R3: cooperative launch silently failed (output never written).
//  R4: ticket+__threadfence fusion = 420 us (device-scope fences across 8
//      non-coherent XCDs serialize; single-block tail reduce). REVERTED.
//  R5: plain 4-dispatch chain, tree reduce with short unrolled chains,
//      wave-per-row rowdot. No atomics, no fences, deterministic.

namespace {

constexpr int F      = 4096;
constexpr int B      = 8192;
constexpr int NTHR   = 256;
constexpr int NSTRIP = 4;                 // 256 thr * float4 = 1024 cols per strip
constexpr int NSLAB  = 256;               // row slabs  -> colsum grid 4 x 256
constexpr int RPS    = B / NSLAB;         // 32 rows per slab
constexpr int NCHUNK = 16;                // reduce1: 256 slabs -> 16 chunks
constexpr int SPC    = NSLAB / NCHUNK;    // 16 slabs per chunk

__device__ __forceinline__ void f4_add(float4& a, const float4 b) {
    a.x += b.x; a.y += b.y; a.z += b.z; a.w += b.w;
}
__device__ __forceinline__ void f4_fma(float& a, const float4 xv, const float4 yv) {
    a = fmaf(xv.x, yv.x, a); a = fmaf(xv.y, yv.y, a);
    a = fmaf(xv.z, yv.z, a); a = fmaf(xv.w, yv.w, a);
}

// Stage 1: block (strip s, slab p) column-sums 32 rows of y into partial[p][...].
// 1024 blocks, fully coalesced float4 streaming.
__global__ __launch_bounds__(NTHR) void colsum_k(
    const float* __restrict__ y, float* __restrict__ partial)
{
    const int s  = blockIdx.x;
    const int p  = blockIdx.y;
    const int c4 = s * NTHR + threadIdx.x;    // float4 column index
    const long row0 = (long)p * RPS;

    float4 acc = {0.f, 0.f, 0.f, 0.f};
#pragma unroll
    for (int r = 0; r < RPS; ++r)
        f4_add(acc, reinterpret_cast<const float4*>(y + (row0 + r) * F)[c4]);
    reinterpret_cast<float4*>(partial + (size_t)p * F)[c4] = acc;
}

// Stage 2: partial2[k][c] = sum of 16 slabs. grid (F/256 x NCHUNK) = 256 blocks.
// Per-thread: 16 independent loads, unrolled (short latency chain).
__global__ __launch_bounds__(NTHR) void reduce1_k(
    const float* __restrict__ partial, float* __restrict__ partial2)
{
    const int c = blockIdx.x * NTHR + threadIdx.x;   // column
    const int k = blockIdx.y;                        // chunk
    float a = 0.f;
#pragma unroll
    for (int i = 0; i < SPC; ++i)
        a += partial[(size_t)(k * SPC + i) * F + c];
    partial2[(size_t)k * F + c] = a;
}

// Stage 3: ysum[c] = sum of 16 chunks. 16 blocks, 16 unrolled loads/thread.
__global__ __launch_bounds__(NTHR) void reduce2_k(
    const float* __restrict__ partial2, float* __restrict__ ysum)
{
    const int c = blockIdx.x * NTHR + threadIdx.x;
    float a = 0.f;
#pragma unroll
    for (int k = 0; k < NCHUNK; ++k)
        a += partial2[(size_t)k * F + c];
    ysum[c] = a;
}

// Stage 4: wave-per-row dot(x[b,:], ysum) -> hardswish -> +noise -> hardtanh.
// 2048 blocks x 4 waves = 8192 rows. No LDS, no __syncthreads.
__global__ __launch_bounds__(NTHR) void rowdot_k(
    const float* __restrict__ x, const float* __restrict__ ysum,
    const float* __restrict__ noise, float* __restrict__ out)
{
    const int wid  = threadIdx.x >> 6;
    const int lane = threadIdx.x & 63;
    const int b    = blockIdx.x * 4 + wid;

    const float4* xr = reinterpret_cast<const float4*>(x + (size_t)b * F);
    const float4* ys = reinterpret_cast<const float4*>(ysum);

    float a0 = 0.f, a1 = 0.f, a2 = 0.f, a3 = 0.f;
#pragma unroll
    for (int g = 0; g < 16; g += 4) {
        f4_fma(a0, xr[(g + 0) * 64 + lane], ys[(g + 0) * 64 + lane]);
        f4_fma(a1, xr[(g + 1) * 64 + lane], ys[(g + 1) * 64 + lane]);
        f4_fma(a2, xr[(g + 2) * 64 + lane], ys[(g + 2) * 64 + lane]);
        f4_fma(a3, xr[(g + 3) * 64 + lane], ys[(g + 3) * 64 + lane]);
    }
    float p = (a0 + a1) + (a2 + a3);
#pragma unroll
    for (int off = 32; off > 0; off >>= 1) p += __shfl_xor(p, off);

    if (lane == 0) {
        const float s = p;
        const float h = s * fminf(fmaxf(s + 3.0f, 0.0f), 6.0f) * (1.0f / 6.0f);
        const float r = h + noise[b];        // logsumexp over singleton == identity
        out[b] = fminf(fmaxf(r, -0.5f), 0.5f);
    }
}

} // namespace

extern "C" void kernel_launch(void* const* d_in, const int* in_sizes, int n_in,
                              void* d_out, int out_size, void* d_ws, size_t ws_size,
                              hipStream_t stream)
{
    const float* x     = (const float*)d_in[0];   // (B, F)
    const float* y     = (const float*)d_in[1];   // (B, F)
    const float* noise = (const float*)d_in[2];   // (B, 1)
    float*       out   = (float*)d_out;           // (B, 1) fp32

    // ws: partial[256][F] (4 MB) | partial2[16][F] (256 KB) | ysum[F] (16 KB)
    float* partial  = (float*)d_ws;
    float* partial2 = partial  + (size_t)NSLAB * F;
    float* ysum     = partial2 + (size_t)NCHUNK * F;

    colsum_k<<<dim3(NSTRIP, NSLAB),    NTHR, 0, stream>>>(y, partial);
    reduce1_k<<<dim3(F / NTHR, NCHUNK), NTHR, 0, stream>>>(partial, partial2);
    reduce2_k<<<F / NTHR,               NTHR, 0, stream>>>(partial2, ysum);
    rowdot_k<<<B / 4,                   NTHR, 0, stream>>>(x, ysum, noise, out);
}